// Round 1
// 472.421 us; speedup vs baseline: 1.0522x; 1.0522x over previous
//
#include <hip/hip_runtime.h>
#include <hip/hip_bf16.h>
#include <math.h>

typedef unsigned short u16;
typedef unsigned int u32;

typedef __bf16 bf16x8 __attribute__((ext_vector_type(8)));
typedef float f32x4 __attribute__((ext_vector_type(4)));

union U8 { uint4 u; u16 s[8]; };

__device__ __forceinline__ float b2f(u16 x) {
    u32 y = ((u32)x) << 16;
    return __builtin_bit_cast(float, y);
}
__device__ __forceinline__ u16 f2b(float f) {
    u32 x = __builtin_bit_cast(u32, f);
    u32 r = x + 0x7fffu + ((x >> 16) & 1u);
    return (u16)(r >> 16);
}
// pack 8 fp32 -> 8 bf16 (one uint4)
__device__ __forceinline__ uint4 cvt8(float4 a, float4 b) {
    U8 o;
    o.s[0] = f2b(a.x); o.s[1] = f2b(a.y); o.s[2] = f2b(a.z); o.s[3] = f2b(a.w);
    o.s[4] = f2b(b.x); o.s[5] = f2b(b.y); o.s[6] = f2b(b.z); o.s[7] = f2b(b.w);
    return o.u;
}

// async global->LDS, 16 B per lane; LDS dest = wave-uniform base + lane*16
__device__ __forceinline__ void gload16(const u16* g, const u16* l) {
    __builtin_amdgcn_global_load_lds(
        (const __attribute__((address_space(1))) void*)g,
        (__attribute__((address_space(3))) void*)l, 16, 0, 0);
}

// ---------------- small kernels ----------------

__global__ void __launch_bounds__(64) zero_ss(float* ss) {
    if (threadIdx.x < 2) ss[threadIdx.x] = 0.f;
}

// sum of squares of Wv (y=0) / Wq (y=1), each 3072*1024 fp32
__global__ void __launch_bounds__(256) sumsq_k(const float* __restrict__ Wv,
                                               const float* __restrict__ Wq,
                                               float* __restrict__ ss, int n) {
    const float* W = (blockIdx.y == 0) ? Wv : Wq;
    float acc = 0.f;
    size_t stride = (size_t)gridDim.x * 256 * 8;
    for (size_t i = ((size_t)blockIdx.x * 256 + threadIdx.x) * 8; i < (size_t)n; i += stride) {
        float4 a = *(const float4*)(W + i);
        float4 b = *(const float4*)(W + i + 4);
        acc += a.x * a.x + a.y * a.y + a.z * a.z + a.w * a.w;
        acc += b.x * b.x + b.y * b.y + b.z * b.z + b.w * b.w;
    }
#pragma unroll
    for (int o = 32; o > 0; o >>= 1) acc += __shfl_down(acc, o, 64);
    __shared__ float red[4];
    int lane = threadIdx.x & 63, wv = threadIdx.x >> 6;
    if (lane == 0) red[wv] = acc;
    __syncthreads();
    if (threadIdx.x == 0) atomicAdd(&ss[blockIdx.y], red[0] + red[1] + red[2] + red[3]);
}

// wvh[h][c][k] = bf16(hm[h,k] * Wv[k,c])  -- fused transpose + 8-head scale
__global__ void __launch_bounds__(256) twvh_k(const float* __restrict__ Wv,
                                              const float* __restrict__ hm,
                                              u16* __restrict__ wvh) {
    __shared__ float t[32][33];
    int cx0 = blockIdx.x * 32;   // c base
    int ky0 = blockIdx.y * 32;   // k base
    int tx = threadIdx.x, ty = threadIdx.y;
#pragma unroll
    for (int j = ty; j < 32; j += 8)
        t[j][tx] = Wv[(size_t)(ky0 + j) * 1024 + cx0 + tx];
    __syncthreads();
    int k = ky0 + tx;
    float hv[8];
#pragma unroll
    for (int h = 0; h < 8; h++) hv[h] = hm[(size_t)h * 3072 + k];
#pragma unroll
    for (int j = ty; j < 32; j += 8) {
        float w = t[tx][j];           // Wv[k][cx0+j]
        int c = cx0 + j;
#pragma unroll
        for (int h = 0; h < 8; h++)
            wvh[(size_t)h * 3145728 + (size_t)c * 3072 + k] = f2b(hv[h] * w);
    }
}

// vb[i] = bf16(v[i]), n elements (generic fp32 -> bf16 cvt, grid-stride)
__global__ void __launch_bounds__(256) cvt_v(const float* __restrict__ v,
                                             u16* __restrict__ vb, int n) {
    size_t stride = (size_t)gridDim.x * 256 * 8;
    for (size_t i = ((size_t)blockIdx.x * 256 + threadIdx.x) * 8; i < (size_t)n; i += stride) {
        float4 a = *(const float4*)(v + i);
        float4 b = *(const float4*)(v + i + 4);
        *(uint4*)(vb + i) = cvt8(a, b);
    }
}

// cb[b*1024 + h*128 + d] = sum_k bv[k]*hm[h,k]*q_[b*128+d, k]   (fp32 acc)
__global__ void __launch_bounds__(256) const_k(const u16* __restrict__ qbuf,
                                               const float* __restrict__ bv,
                                               const float* __restrict__ hm,
                                               float* __restrict__ cb) {
    int idx = blockIdx.x * 256 + threadIdx.x;  // 0..16383
    int b = idx >> 10, hd = idx & 1023, h = hd >> 7, d = hd & 127;
    const u16* qr = qbuf + ((size_t)b * 128 + d) * 3072;
    const float* hr = hm + (size_t)h * 3072;
    float acc = 0.f;
    for (int k = 0; k < 3072; k += 8) {
        U8 uq; uq.u = *(const uint4*)(qr + k);
        float4 h0 = *(const float4*)(hr + k);
        float4 h1 = *(const float4*)(hr + k + 4);
        float4 b0 = *(const float4*)(bv + k);
        float4 b1 = *(const float4*)(bv + k + 4);
        acc += b2f(uq.s[0]) * h0.x * b0.x + b2f(uq.s[1]) * h0.y * b0.y +
               b2f(uq.s[2]) * h0.z * b0.z + b2f(uq.s[3]) * h0.w * b0.w +
               b2f(uq.s[4]) * h1.x * b1.x + b2f(uq.s[5]) * h1.y * b1.y +
               b2f(uq.s[6]) * h1.z * b1.z + b2f(uq.s[7]) * h1.w * b1.w;
    }
    cb[idx] = acc;
}

// ---------------- main BT-GEMM (global_load_lds + swizzled layout) ----------------
// C(M x N) = A(M x kdim) * Bt(N x kdim)^T, 128x128 tile, BK=32, 4 waves 2x2.
// LDS swizzle invariant: LDS[row][sg] holds global k-group sg ^ ((row>>1)&3)
//   -> frag ds_read_b128 <=2-way bank-aliased (free).
// bf16 operands are staged with global_load_lds (wave-uniform LDS base + lane*16,
// LINEAR dest) by PRE-SWIZZLING the per-lane global source (rule #21 / m173):
//   lane l, issue i: local row R = 64i + 16*wv + (l>>2), stored group sg = l&3,
//   global group qc = sg ^ ((l>>3)&3)   [ == sg ^ ((R>>1)&3) ].
// One __syncthreads per K-iter; 2 LDS buffers; stage issued before ds_read+MFMA
// so loads are in flight under compute (T3 minimum 2-phase, m97 structure).
// EPI 0: qbuf[gr*3072+gc] = bf16(acc*scale + bq[gc])           (M=2048,N=3072)
// EPI 1: monolithic T: M=2048 (b,d), N=8192 (h,c);
//        tbuf[b][h][d][c] = bf16(acc)                          (K=3072)
// EPI 2: per-batch z=b: out[((b*8+h)*1024+n)*128+d]            (M=N=K=1024)
template <int EPI, bool A_BF16>
__global__ void __launch_bounds__(256)
gemm_bt(const void* __restrict__ Ap, const u16* __restrict__ Bp, void* __restrict__ C,
        const float* __restrict__ ss, int ss_idx, const float* __restrict__ g,
        const float* __restrict__ bias, const float* __restrict__ cb,
        const float* __restrict__ hbias, int kdim, size_t abatch, size_t bbatch) {
    constexpr int BK = 32;
    __shared__ __align__(16) u16 sA[2][128 * BK];
    __shared__ __align__(16) u16 sB[2][128 * BK];

    const int tid = threadIdx.x;
    const int lane = tid & 63, wv = tid >> 6;
    const int wm = (wv & 1) * 64, wn = (wv >> 1) * 64;
    const int lr = lane & 15, quad = lane >> 4;
    const int z = blockIdx.z;
    const int arow0 = blockIdx.y * 128;
    const int bcol0 = blockIdx.x * 128;

    const size_t aoff = (size_t)z * abatch;
    const size_t boff = (size_t)z * bbatch;

    // ---- gload_lds staging geometry ----
    const int srow = 16 * wv + (lane >> 2);          // issue-0 local row
    const int qcg  = (lane & 3) ^ ((lane >> 3) & 3); // pre-swizzled global k-group
    const int lb0  = wv * 512;                       // u16 offset: wv*16 rows * 32
    const int lb1  = lb0 + 2048;                     // +64 rows

    const u16* gB0 = Bp + boff + (size_t)(bcol0 + srow) * kdim + qcg * 8;
    const u16* gB1 = gB0 + (size_t)64 * kdim;

    // fp32-A reg-staging map (fallback path only)
    const int r0 = tid >> 2, c0 = (tid & 3) * 8;
    const int w0 = r0 * 32 + (((tid & 3) ^ ((tid >> 3) & 3)) * 8);
    const int w1 = w0 + 2048;

    const u16* gA0 = nullptr; const u16* gA1 = nullptr;
    const float* fA0 = nullptr; const float* fA1 = nullptr;
    if constexpr (A_BF16) {
        gA0 = (const u16*)Ap + aoff + (size_t)(arow0 + srow) * kdim + qcg * 8;
        gA1 = gA0 + (size_t)64 * kdim;
    } else {
        fA0 = (const float*)Ap + aoff + (size_t)(arow0 + r0) * kdim + c0;
        fA1 = fA0 + (size_t)64 * kdim;
    }

    // swizzled read col-offset
    const int rsw = (quad ^ ((lr >> 1) & 3)) * 8;

    // ---- prologue: stage tile 0 into buffer 0 ----
    if constexpr (A_BF16) {
        gload16(gA0, sA[0] + lb0);
        gload16(gA1, sA[0] + lb1);
        gA0 += BK; gA1 += BK;
    } else {
        float4 x0 = *(const float4*)fA0, x1 = *(const float4*)(fA0 + 4);
        float4 y0 = *(const float4*)fA1, y1 = *(const float4*)(fA1 + 4);
        *(uint4*)(sA[0] + w0) = cvt8(x0, x1);
        *(uint4*)(sA[0] + w1) = cvt8(y0, y1);
        fA0 += BK; fA1 += BK;
    }
    gload16(gB0, sB[0] + lb0);
    gload16(gB1, sB[0] + lb1);
    gB0 += BK; gB1 += BK;

    f32x4 acc[4][4];
#pragma unroll
    for (int im = 0; im < 4; im++)
#pragma unroll
        for (int in = 0; in < 4; in++) acc[im][in] = (f32x4){0.f, 0.f, 0.f, 0.f};

    __syncthreads();  // drains vmcnt -> tile 0 resident

    int p = 0;
    for (int kt = 0; kt < kdim; kt += BK) {
        const bool more = (kt + BK < kdim);

        // issue next-tile staging FIRST so loads fly under ds_read+MFMA
        float4 ax0, ax1, ay0, ay1;
        if (more) {
            if constexpr (A_BF16) {
                gload16(gA0, sA[p ^ 1] + lb0);
                gload16(gA1, sA[p ^ 1] + lb1);
                gA0 += BK; gA1 += BK;
            } else {
                ax0 = *(const float4*)fA0; ax1 = *(const float4*)(fA0 + 4);
                ay0 = *(const float4*)fA1; ay1 = *(const float4*)(fA1 + 4);
                fA0 += BK; fA1 += BK;
            }
            gload16(gB0, sB[p ^ 1] + lb0);
            gload16(gB1, sB[p ^ 1] + lb1);
            gB0 += BK; gB1 += BK;
        }

        const u16* sAp = sA[p];
        const u16* sBp = sB[p];
        bf16x8 af[4], bfr[4];
#pragma unroll
        for (int im = 0; im < 4; im++)
            af[im] = *(const bf16x8*)(sAp + (wm + im * 16 + lr) * 32 + rsw);
#pragma unroll
        for (int in = 0; in < 4; in++)
            bfr[in] = *(const bf16x8*)(sBp + (wn + in * 16 + lr) * 32 + rsw);
#pragma unroll
        for (int im = 0; im < 4; im++)
#pragma unroll
            for (int in = 0; in < 4; in++)
                acc[im][in] = __builtin_amdgcn_mfma_f32_16x16x32_bf16(af[im], bfr[in], acc[im][in], 0, 0, 0);

        if (more) {
            if constexpr (!A_BF16) {
                u16* dA = sA[p ^ 1];
                *(uint4*)(dA + w0) = cvt8(ax0, ax1);
                *(uint4*)(dA + w1) = cvt8(ay0, ay1);
            }
        }
        __syncthreads();  // vmcnt(0)+lgkmcnt(0) drain: next tile staged, reads done
        p ^= 1;
    }

    float scale = 1.f;
    if constexpr (EPI == 0 || EPI == 2) scale = g[0] / sqrtf(ss[ss_idx]);

#pragma unroll
    for (int im = 0; im < 4; im++) {
#pragma unroll
        for (int in = 0; in < 4; in++) {
#pragma unroll
            for (int reg = 0; reg < 4; reg++) {
                int gr = arow0 + wm + im * 16 + quad * 4 + reg;  // row (M)
                int gc = bcol0 + wn + in * 16 + lr;              // col (N)
                float val = acc[im][in][reg];
                if constexpr (EPI == 0) {
                    ((u16*)C)[(size_t)gr * 3072 + gc] = f2b(val * scale + bias[gc]);
                } else if constexpr (EPI == 1) {
                    // gr = b*128+d, gc = h*1024+c -> tbuf[b][h][d][c]; lane-coalesced in c
                    size_t idx = (((size_t)(gr >> 7) * 8 + (gc >> 10)) * 128 + (gr & 127)) * 1024
                               + (gc & 1023);
                    ((u16*)C)[idx] = f2b(val);
                } else {
                    int h = gc >> 7, d = gc & 127;
                    float o = val * scale + cb[(size_t)z * 1024 + gc] + hbias[h];
                    ((float*)C)[(((size_t)z * 8 + h) * 1024 + gr) * 128 + d] = o;
                }
            }
        }
    }
}

// ---------------- launch ----------------

extern "C" void kernel_launch(void* const* d_in, const int* in_sizes, int n_in,
                              void* d_out, int out_size, void* d_ws, size_t ws_size,
                              hipStream_t stream) {
    (void)in_sizes; (void)n_in; (void)out_size;
    const float* v  = (const float*)d_in[0];   // (16,1024,1024) fp32
    const float* q  = (const float*)d_in[1];   // (16,128,1024)  fp32
    const float* Wv = (const float*)d_in[2];   // (3072,1024)    fp32
    const float* gv = (const float*)d_in[3];
    const float* bv = (const float*)d_in[4];   // (3072)
    const float* Wq = (const float*)d_in[5];   // (3072,1024)
    const float* gq = (const float*)d_in[6];
    const float* bq = (const float*)d_in[7];   // (3072)
    const float* hm = (const float*)d_in[8];   // (8,3072)
    const float* hb = (const float*)d_in[9];   // (8)
    float* out = (float*)d_out;                // fp32 output (16,8,1024,128) = 67 MB

    // workspace layout (floor 46.2 MB; +33.5 MB vb if available)
    char* ws = (char*)d_ws;
    float* ss   = (float*)ws;                          // 256 B
    float* cb   = (float*)(ws + 256);                  // 64 KB
    u16*   qbuf = (u16*)(ws + 256 + 65536);            // 2048*3072 bf16 = 12 MB
    u16*   tbuf = (u16*)(ws + 256 + 65536 + 12582912); // 16*8*128*1024 bf16 = 33.5 MB
    u16*   vb   = (u16*)(ws + 256 + 65536 + 12582912 + 33554432);  // optional 33.5 MB
    const size_t need_vb = 256 + 65536 + 12582912 + 33554432 + 33554432;  // ~80.2 MB
    const bool fullfat = (ws_size >= need_vb);

    // scratch in d_out (67.1 MB), all dead before gemm<2> writes out:
    //   wvh 8*1024*3072 bf16 = 50.33 MB | qb 2048*1024 bf16 = 4.19 MB | wqb 3072*1024 bf16 = 6.29 MB
    u16* wvh = (u16*)d_out;
    u16* qb  = (u16*)((char*)d_out + 50331648);
    u16* wqb = (u16*)((char*)d_out + 54525952);   // ends at 60.8 MB < 67.1 MB

    zero_ss<<<1, 64, 0, stream>>>(ss);
    sumsq_k<<<dim3(256, 2), 256, 0, stream>>>(Wv, Wq, ss, 3072 * 1024);

    // wvh[h][c][k] = bf16(hm[h,k]*Wv[k,c])
    twvh_k<<<dim3(32, 96), dim3(32, 8), 0, stream>>>(Wv, hm, wvh);

    // bf16 copies of q and Wq so gemm<0> takes the pure-bf16 gload_lds path
    cvt_v<<<1024, 256, 0, stream>>>(q, qb, 2097152);
    cvt_v<<<1536, 256, 0, stream>>>(Wq, wqb, 3145728);

    // q_ = q * wn(Wq)^T + bq   (2048 x 3072)
    gemm_bt<0, true><<<dim3(24, 16, 1), 256, 0, stream>>>(
        qb, wqb, qbuf, ss, 1, gq, bq, nullptr, nullptr, 1024, 0, 0);

    // cb[b,hd] = sum_k bv*hm*q_
    const_k<<<64, 256, 0, stream>>>(qbuf, bv, hm, cb);

    // T[b,h,d,c] = sum_k q_[b,d,k] * wvh[h,c,k]  -- ONE GEMM: M=2048, N=8192, K=3072
    gemm_bt<1, true><<<dim3(64, 16, 1), 256, 0, stream>>>(
        qbuf, wvh, tbuf, ss, 0, nullptr, nullptr, nullptr, nullptr, 3072, 0, 0);

    // logits[b,h,n,d] = scale_v * sum_c v[b,n,c]*T[b,hd,c] + cb[b,hd] + hbias[h]
    if (fullfat) {
        cvt_v<<<4096, 256, 0, stream>>>(v, vb, 16777216);
        gemm_bt<2, true><<<dim3(8, 8, 16), 256, 0, stream>>>(
            vb, tbuf, out, ss, 0, gv, nullptr, cb, hb, 1024, 1048576, 1048576);
    } else {
        gemm_bt<2, false><<<dim3(8, 8, 16), 256, 0, stream>>>(
            v, tbuf, out, ss, 0, gv, nullptr, cb, hb, 1024, 1048576, 1048576);
    }
}

// Round 2
// 410.991 us; speedup vs baseline: 1.2095x; 1.1495x over previous
//
#include <hip/hip_runtime.h>
#include <hip/hip_bf16.h>
#include <math.h>

typedef unsigned short u16;
typedef unsigned int u32;

typedef __bf16 bf16x8 __attribute__((ext_vector_type(8)));
typedef float f32x4 __attribute__((ext_vector_type(4)));

union U8 { uint4 u; u16 s[8]; };

__device__ __forceinline__ float b2f(u16 x) {
    u32 y = ((u32)x) << 16;
    return __builtin_bit_cast(float, y);
}
__device__ __forceinline__ u16 f2b(float f) {
    u32 x = __builtin_bit_cast(u32, f);
    u32 r = x + 0x7fffu + ((x >> 16) & 1u);
    return (u16)(r >> 16);
}
// pack 8 fp32 -> 8 bf16 (one uint4)
__device__ __forceinline__ uint4 cvt8(float4 a, float4 b) {
    U8 o;
    o.s[0] = f2b(a.x); o.s[1] = f2b(a.y); o.s[2] = f2b(a.z); o.s[3] = f2b(a.w);
    o.s[4] = f2b(b.x); o.s[5] = f2b(b.y); o.s[6] = f2b(b.z); o.s[7] = f2b(b.w);
    return o.u;
}

// async global->LDS, 16 B per lane; LDS dest = wave-uniform base + lane*16
__device__ __forceinline__ void gload16(const u16* g, const u16* l) {
    __builtin_amdgcn_global_load_lds(
        (const __attribute__((address_space(1))) void*)g,
        (__attribute__((address_space(3))) void*)l, 16, 0, 0);
}

// ---------------- small kernels ----------------

__global__ void __launch_bounds__(64) zero_ss(float* ss) {
    if (threadIdx.x < 2) ss[threadIdx.x] = 0.f;
}

// sum of squares of Wv (y=0) / Wq (y=1), each 3072*1024 fp32
__global__ void __launch_bounds__(256) sumsq_k(const float* __restrict__ Wv,
                                               const float* __restrict__ Wq,
                                               float* __restrict__ ss, int n) {
    const float* W = (blockIdx.y == 0) ? Wv : Wq;
    float acc = 0.f;
    size_t stride = (size_t)gridDim.x * 256 * 8;
    for (size_t i = ((size_t)blockIdx.x * 256 + threadIdx.x) * 8; i < (size_t)n; i += stride) {
        float4 a = *(const float4*)(W + i);
        float4 b = *(const float4*)(W + i + 4);
        acc += a.x * a.x + a.y * a.y + a.z * a.z + a.w * a.w;
        acc += b.x * b.x + b.y * b.y + b.z * b.z + b.w * b.w;
    }
#pragma unroll
    for (int o = 32; o > 0; o >>= 1) acc += __shfl_down(acc, o, 64);
    __shared__ float red[4];
    int lane = threadIdx.x & 63, wv = threadIdx.x >> 6;
    if (lane == 0) red[wv] = acc;
    __syncthreads();
    if (threadIdx.x == 0) atomicAdd(&ss[blockIdx.y], red[0] + red[1] + red[2] + red[3]);
}

// wvh[h][c][k] = bf16(hm[h,k] * Wv[k,c])  -- fused transpose + 8-head scale
__global__ void __launch_bounds__(256) twvh_k(const float* __restrict__ Wv,
                                              const float* __restrict__ hm,
                                              u16* __restrict__ wvh) {
    __shared__ float t[32][33];
    int cx0 = blockIdx.x * 32;   // c base
    int ky0 = blockIdx.y * 32;   // k base
    int tx = threadIdx.x, ty = threadIdx.y;
#pragma unroll
    for (int j = ty; j < 32; j += 8)
        t[j][tx] = Wv[(size_t)(ky0 + j) * 1024 + cx0 + tx];
    __syncthreads();
    int k = ky0 + tx;
    float hv[8];
#pragma unroll
    for (int h = 0; h < 8; h++) hv[h] = hm[(size_t)h * 3072 + k];
#pragma unroll
    for (int j = ty; j < 32; j += 8) {
        float w = t[tx][j];           // Wv[k][cx0+j]
        int c = cx0 + j;
#pragma unroll
        for (int h = 0; h < 8; h++)
            wvh[(size_t)h * 3145728 + (size_t)c * 3072 + k] = f2b(hv[h] * w);
    }
}

// vb[i] = bf16(v[i]), n elements (generic fp32 -> bf16 cvt, grid-stride)
__global__ void __launch_bounds__(256) cvt_v(const float* __restrict__ v,
                                             u16* __restrict__ vb, int n) {
    size_t stride = (size_t)gridDim.x * 256 * 8;
    for (size_t i = ((size_t)blockIdx.x * 256 + threadIdx.x) * 8; i < (size_t)n; i += stride) {
        float4 a = *(const float4*)(v + i);
        float4 b = *(const float4*)(v + i + 4);
        *(uint4*)(vb + i) = cvt8(a, b);
    }
}

// cb[b*1024 + h*128 + d] = sum_k bv[k]*hm[h,k]*q_[b*128+d, k]   (fp32 acc)
__global__ void __launch_bounds__(256) const_k(const u16* __restrict__ qbuf,
                                               const float* __restrict__ bv,
                                               const float* __restrict__ hm,
                                               float* __restrict__ cb) {
    int idx = blockIdx.x * 256 + threadIdx.x;  // 0..16383
    int b = idx >> 10, hd = idx & 1023, h = hd >> 7, d = hd & 127;
    const u16* qr = qbuf + ((size_t)b * 128 + d) * 3072;
    const float* hr = hm + (size_t)h * 3072;
    float acc = 0.f;
    for (int k = 0; k < 3072; k += 8) {
        U8 uq; uq.u = *(const uint4*)(qr + k);
        float4 h0 = *(const float4*)(hr + k);
        float4 h1 = *(const float4*)(hr + k + 4);
        float4 b0 = *(const float4*)(bv + k);
        float4 b1 = *(const float4*)(bv + k + 4);
        acc += b2f(uq.s[0]) * h0.x * b0.x + b2f(uq.s[1]) * h0.y * b0.y +
               b2f(uq.s[2]) * h0.z * b0.z + b2f(uq.s[3]) * h0.w * b0.w +
               b2f(uq.s[4]) * h1.x * b1.x + b2f(uq.s[5]) * h1.y * b1.y +
               b2f(uq.s[6]) * h1.z * b1.z + b2f(uq.s[7]) * h1.w * b1.w;
    }
    cb[idx] = acc;
}

// ---------------- legacy 128x128 BT-GEMM (2-phase, __syncthreads) ----------------
// kept for EPI 0 (small N, more blocks) and the fp32-A fallback of EPI 2.
template <int EPI, bool A_BF16>
__global__ void __launch_bounds__(256)
gemm_bt(const void* __restrict__ Ap, const u16* __restrict__ Bp, void* __restrict__ C,
        const float* __restrict__ ss, int ss_idx, const float* __restrict__ g,
        const float* __restrict__ bias, const float* __restrict__ cb,
        const float* __restrict__ hbias, int kdim, size_t abatch, size_t bbatch) {
    constexpr int BK = 32;
    __shared__ __align__(16) u16 sA[2][128 * BK];
    __shared__ __align__(16) u16 sB[2][128 * BK];

    const int tid = threadIdx.x;
    const int lane = tid & 63, wv = tid >> 6;
    const int wm = (wv & 1) * 64, wn = (wv >> 1) * 64;
    const int lr = lane & 15, quad = lane >> 4;
    const int z = blockIdx.z;
    const int arow0 = blockIdx.y * 128;
    const int bcol0 = blockIdx.x * 128;

    const size_t aoff = (size_t)z * abatch;
    const size_t boff = (size_t)z * bbatch;

    const int srow = 16 * wv + (lane >> 2);
    const int qcg  = (lane & 3) ^ ((lane >> 3) & 3);
    const int lb0  = wv * 512;
    const int lb1  = lb0 + 2048;

    const u16* gB0 = Bp + boff + (size_t)(bcol0 + srow) * kdim + qcg * 8;
    const u16* gB1 = gB0 + (size_t)64 * kdim;

    const int r0 = tid >> 2, c0 = (tid & 3) * 8;
    const int w0 = r0 * 32 + (((tid & 3) ^ ((tid >> 3) & 3)) * 8);
    const int w1 = w0 + 2048;

    const u16* gA0 = nullptr; const u16* gA1 = nullptr;
    const float* fA0 = nullptr; const float* fA1 = nullptr;
    if constexpr (A_BF16) {
        gA0 = (const u16*)Ap + aoff + (size_t)(arow0 + srow) * kdim + qcg * 8;
        gA1 = gA0 + (size_t)64 * kdim;
    } else {
        fA0 = (const float*)Ap + aoff + (size_t)(arow0 + r0) * kdim + c0;
        fA1 = fA0 + (size_t)64 * kdim;
    }

    const int rsw = (quad ^ ((lr >> 1) & 3)) * 8;

    if constexpr (A_BF16) {
        gload16(gA0, sA[0] + lb0);
        gload16(gA1, sA[0] + lb1);
        gA0 += BK; gA1 += BK;
    } else {
        float4 x0 = *(const float4*)fA0, x1 = *(const float4*)(fA0 + 4);
        float4 y0 = *(const float4*)fA1, y1 = *(const float4*)(fA1 + 4);
        *(uint4*)(sA[0] + w0) = cvt8(x0, x1);
        *(uint4*)(sA[0] + w1) = cvt8(y0, y1);
        fA0 += BK; fA1 += BK;
    }
    gload16(gB0, sB[0] + lb0);
    gload16(gB1, sB[0] + lb1);
    gB0 += BK; gB1 += BK;

    f32x4 acc[4][4];
#pragma unroll
    for (int im = 0; im < 4; im++)
#pragma unroll
        for (int in = 0; in < 4; in++) acc[im][in] = (f32x4){0.f, 0.f, 0.f, 0.f};

    __syncthreads();

    int p = 0;
    for (int kt = 0; kt < kdim; kt += BK) {
        const bool more = (kt + BK < kdim);

        float4 ax0, ax1, ay0, ay1;
        if (more) {
            if constexpr (A_BF16) {
                gload16(gA0, sA[p ^ 1] + lb0);
                gload16(gA1, sA[p ^ 1] + lb1);
                gA0 += BK; gA1 += BK;
            } else {
                ax0 = *(const float4*)fA0; ax1 = *(const float4*)(fA0 + 4);
                ay0 = *(const float4*)fA1; ay1 = *(const float4*)(fA1 + 4);
                fA0 += BK; fA1 += BK;
            }
            gload16(gB0, sB[p ^ 1] + lb0);
            gload16(gB1, sB[p ^ 1] + lb1);
            gB0 += BK; gB1 += BK;
        }

        const u16* sAp = sA[p];
        const u16* sBp = sB[p];
        bf16x8 af[4], bfr[4];
#pragma unroll
        for (int im = 0; im < 4; im++)
            af[im] = *(const bf16x8*)(sAp + (wm + im * 16 + lr) * 32 + rsw);
#pragma unroll
        for (int in = 0; in < 4; in++)
            bfr[in] = *(const bf16x8*)(sBp + (wn + in * 16 + lr) * 32 + rsw);
#pragma unroll
        for (int im = 0; im < 4; im++)
#pragma unroll
            for (int in = 0; in < 4; in++)
                acc[im][in] = __builtin_amdgcn_mfma_f32_16x16x32_bf16(af[im], bfr[in], acc[im][in], 0, 0, 0);

        if (more) {
            if constexpr (!A_BF16) {
                u16* dA = sA[p ^ 1];
                *(uint4*)(dA + w0) = cvt8(ax0, ax1);
                *(uint4*)(dA + w1) = cvt8(ay0, ay1);
            }
        }
        __syncthreads();
        p ^= 1;
    }

    float scale = 1.f;
    if constexpr (EPI == 0 || EPI == 2) scale = g[0] / sqrtf(ss[ss_idx]);

#pragma unroll
    for (int im = 0; im < 4; im++) {
#pragma unroll
        for (int in = 0; in < 4; in++) {
#pragma unroll
            for (int reg = 0; reg < 4; reg++) {
                int gr = arow0 + wm + im * 16 + quad * 4 + reg;
                int gc = bcol0 + wn + in * 16 + lr;
                float val = acc[im][in][reg];
                if constexpr (EPI == 0) {
                    ((u16*)C)[(size_t)gr * 3072 + gc] = f2b(val * scale + bias[gc]);
                } else if constexpr (EPI == 1) {
                    size_t idx = (((size_t)(gr >> 7) * 8 + (gc >> 10)) * 128 + (gr & 127)) * 1024
                               + (gc & 1023);
                    ((u16*)C)[idx] = f2b(val);
                } else {
                    int h = gc >> 7, d = gc & 127;
                    float o = val * scale + cb[(size_t)z * 1024 + gc] + hbias[h];
                    ((float*)C)[(((size_t)z * 8 + h) * 1024 + gr) * 128 + d] = o;
                }
            }
        }
    }
}

// ---------------- 256x256 8-phase BT-GEMM (m201 structure: T1+T2+T3+T4+T5) ----------------
// C(M x N) = A(M x kdim) * Bt(N x kdim)^T. BM=BN=256, BK=64, 8 waves (2M x 4N),
// per-wave output 128x64 -> acc[8][4]. LDS 128 KiB: sA/sB[2 dbuf][256][64] bf16.
//
// st_16x32 swizzle (T2): LDS[row][g] (g = 16B group 0..7) holds global[row][g ^ ((row&4)?2:0)].
// Applied by pre-swizzling gload_lds's per-lane GLOBAL source (LDS dest stays linear),
// and XOR-ing the ds_read group the same way (same involution both sides).
//
// Phase structure per K-tile t (dbuf d = t&1), (ks,mh) quadrants, 16 MFMA each:
//   p0 (ks0,mh0): read B-ks0 frags(4)+A-mh0-ks0(4); stage A-calls{0,2} of t+1 -> dbuf d^1
//   p1 (ks0,mh1): read A-mh1-ks0(4);                stage B-calls{0,1}
//   p2 (ks1,mh0): read B-ks1(4)+A-mh0-ks1(4);       stage B-calls{2,3}
//   p3 (ks1,mh1): read A-mh1-ks1(4);                stage A-calls{1,3}
// Counted vmcnt gates (T4, never 0 mid-loop), placed after MFMA before bar2:
//   p0: vmcnt(2)  -- drains t-1.p3's A{1,3} (needed by this tile's p1/p3 reads)
//   p3: vmcnt(2)  -- drains t.p0-p2 (A{0,2}+B of t+1, needed by t+1.p0)
// Last tile (no staging): p0 uses vmcnt(0) once. Stages always target the
// opposite dbuf whose last reads finished >=1 barrier earlier -> race-free.
template <int EPI>
__global__ void __launch_bounds__(512, 2)
gemm8p(const u16* __restrict__ Ap, const u16* __restrict__ Bp, void* __restrict__ C,
       const float* __restrict__ ss, const float* __restrict__ g,
       const float* __restrict__ cb, const float* __restrict__ hbias,
       int kdim, size_t abatch, size_t bbatch) {
    __shared__ __align__(16) u16 sA[2][256 * 64];
    __shared__ __align__(16) u16 sB[2][256 * 64];

    const int tid = threadIdx.x;
    const int lane = tid & 63, wv = tid >> 6;
    const int wm = (wv & 1) * 128;            // M warp offset (2 warps)
    const int wn = (wv >> 1) * 64;            // N warp offset (4 warps)
    const int lr = lane & 15, quad = lane >> 4;
    const int z = blockIdx.z;

    int bx, by;
    if constexpr (EPI == 1) {
        // T1 bijective XCD swizzle: 256 blocks, 32/XCD -> each XCD owns one by-row
        int orig = blockIdx.y * 32 + blockIdx.x;       // gridDim = (32,8)
        int wg = (orig & 7) * 32 + (orig >> 3);
        bx = wg & 31; by = wg >> 5;
    } else {
        bx = blockIdx.x; by = blockIdx.y;
    }
    const int arow0 = by * 256, bcol0 = bx * 256;

    const size_t aoff = (size_t)z * abatch, boff = (size_t)z * bbatch;

    // staging lane map: call = 64 rows x 64 cols (8KB); thread covers row tid>>3,
    // 16B-group tid&7, with pre-swizzled global group (row&4 -> ^2)
    const int sg = (tid & 7) ^ (((tid >> 5) & 1) << 1);
    const u16* gA = Ap + aoff + (size_t)(arow0 + (tid >> 3)) * kdim + sg * 8;
    const u16* gB = Bp + boff + (size_t)(bcol0 + (tid >> 3)) * kdim + sg * 8;
    const size_t ldk64 = (size_t)64 * kdim;    // 64-row call stride (elements)
    const int ldst = wv * 512;                 // wave's u16 offset within a call

    // frag read bases (u16): row*64 + swizzled group*8; row&4 == lr&4
    const int qz = quad ^ ((lr >> 1) & 2);
    const int rbA = (wm + lr) * 64 + qz * 8;
    const int rbB = (wn + lr) * 64 + qz * 8;

    f32x4 acc[8][4];
#pragma unroll
    for (int im = 0; im < 8; im++)
#pragma unroll
        for (int in = 0; in < 4; in++) acc[im][in] = (f32x4){0.f, 0.f, 0.f, 0.f};

    // ---- prologue: stage K-tile 0 into dbuf 0, full drain ----
    gload16(gA + 0 * ldk64, sA[0] + 0 * 4096 + ldst);
    gload16(gA + 1 * ldk64, sA[0] + 1 * 4096 + ldst);
    gload16(gA + 2 * ldk64, sA[0] + 2 * 4096 + ldst);
    gload16(gA + 3 * ldk64, sA[0] + 3 * 4096 + ldst);
    gload16(gB + 0 * ldk64, sB[0] + 0 * 4096 + ldst);
    gload16(gB + 1 * ldk64, sB[0] + 1 * 4096 + ldst);
    gload16(gB + 2 * ldk64, sB[0] + 2 * 4096 + ldst);
    gload16(gB + 3 * ldk64, sB[0] + 3 * 4096 + ldst);
    gA += 64; gB += 64;                        // -> K-tile 1 columns
    asm volatile("s_waitcnt vmcnt(0)" ::: "memory");
    __builtin_amdgcn_s_barrier();

    const int NT = kdim >> 6;
    bf16x8 af[4], bfr[4];
    for (int t = 0; t < NT; ++t) {
        const u16* sAd = sA[t & 1];
        const u16* sBd = sB[t & 1];
        u16* dA = sA[(t & 1) ^ 1];
        u16* dB = sB[(t & 1) ^ 1];
        const bool stg = (t + 1 < NT);

        // ---- phase 0: ks=0, mh=0 ----
#pragma unroll
        for (int n = 0; n < 4; n++) bfr[n] = *(const bf16x8*)(sBd + rbB + n * 1024);
#pragma unroll
        for (int j = 0; j < 4; j++) af[j] = *(const bf16x8*)(sAd + rbA + j * 1024);
        if (stg) {
            gload16(gA + 0 * ldk64, dA + 0 * 4096 + ldst);
            gload16(gA + 2 * ldk64, dA + 2 * 4096 + ldst);
        }
        __builtin_amdgcn_s_barrier();
        __builtin_amdgcn_s_setprio(1);
#pragma unroll
        for (int j = 0; j < 4; j++)
#pragma unroll
            for (int n = 0; n < 4; n++)
                acc[j][n] = __builtin_amdgcn_mfma_f32_16x16x32_bf16(af[j], bfr[n], acc[j][n], 0, 0, 0);
        __builtin_amdgcn_s_setprio(0);
        if (stg) asm volatile("s_waitcnt vmcnt(2)" ::: "memory");
        else     asm volatile("s_waitcnt vmcnt(0)" ::: "memory");
        __builtin_amdgcn_s_barrier();

        // ---- phase 1: ks=0, mh=1 ----
#pragma unroll
        for (int j = 0; j < 4; j++) af[j] = *(const bf16x8*)(sAd + rbA + (4 + j) * 1024);
        if (stg) {
            gload16(gB + 0 * ldk64, dB + 0 * 4096 + ldst);
            gload16(gB + 1 * ldk64, dB + 1 * 4096 + ldst);
        }
        __builtin_amdgcn_s_barrier();
        __builtin_amdgcn_s_setprio(1);
#pragma unroll
        for (int j = 0; j < 4; j++)
#pragma unroll
            for (int n = 0; n < 4; n++)
                acc[4 + j][n] = __builtin_amdgcn_mfma_f32_16x16x32_bf16(af[j], bfr[n], acc[4 + j][n], 0, 0, 0);
        __builtin_amdgcn_s_setprio(0);
        __builtin_amdgcn_s_barrier();

        // ---- phase 2: ks=1, mh=0 ----
#pragma unroll
        for (int n = 0; n < 4; n++) bfr[n] = *(const bf16x8*)(sBd + rbB + n * 1024 + 32);
#pragma unroll
        for (int j = 0; j < 4; j++) af[j] = *(const bf16x8*)(sAd + rbA + j * 1024 + 32);
        if (stg) {
            gload16(gB + 2 * ldk64, dB + 2 * 4096 + ldst);
            gload16(gB + 3 * ldk64, dB + 3 * 4096 + ldst);
        }
        __builtin_amdgcn_s_barrier();
        __builtin_amdgcn_s_setprio(1);
#pragma unroll
        for (int j = 0; j < 4; j++)
#pragma unroll
            for (int n = 0; n < 4; n++)
                acc[j][n] = __builtin_amdgcn_mfma_f32_16x16x32_bf16(af[j], bfr[n], acc[j][n], 0, 0, 0);
        __builtin_amdgcn_s_setprio(0);
        __builtin_amdgcn_s_barrier();

        // ---- phase 3: ks=1, mh=1 ----
#pragma unroll
        for (int j = 0; j < 4; j++) af[j] = *(const bf16x8*)(sAd + rbA + (4 + j) * 1024 + 32);
        if (stg) {
            gload16(gA + 1 * ldk64, dA + 1 * 4096 + ldst);
            gload16(gA + 3 * ldk64, dA + 3 * 4096 + ldst);
        }
        __builtin_amdgcn_s_barrier();
        __builtin_amdgcn_s_setprio(1);
#pragma unroll
        for (int j = 0; j < 4; j++)
#pragma unroll
            for (int n = 0; n < 4; n++)
                acc[4 + j][n] = __builtin_amdgcn_mfma_f32_16x16x32_bf16(af[j], bfr[n], acc[4 + j][n], 0, 0, 0);
        __builtin_amdgcn_s_setprio(0);
        if (stg) asm volatile("s_waitcnt vmcnt(2)" ::: "memory");
        __builtin_amdgcn_s_barrier();

        gA += 64; gB += 64;
    }

    // ---- epilogue ----
    float scale = 1.f;
    if constexpr (EPI == 2) scale = g[0] / sqrtf(ss[0]);

#pragma unroll
    for (int im = 0; im < 8; im++) {
#pragma unroll
        for (int in = 0; in < 4; in++) {
#pragma unroll
            for (int reg = 0; reg < 4; reg++) {
                int gr = arow0 + wm + im * 16 + quad * 4 + reg;  // row (M)
                int gc = bcol0 + wn + in * 16 + lr;              // col (N)
                float val = acc[im][in][reg];
                if constexpr (EPI == 1) {
                    // gr = b*128+d (M=2048), gc = h*1024+c (N=8192) -> tbuf[b][h][d][c]
                    size_t idx = (((size_t)(gr >> 7) * 8 + (gc >> 10)) * 128 + (gr & 127)) * 1024
                               + (gc & 1023);
                    ((u16*)C)[idx] = f2b(val);
                } else {
                    int h = gc >> 7, d = gc & 127;
                    float o = val * scale + cb[(size_t)z * 1024 + gc] + hbias[h];
                    ((float*)C)[(((size_t)z * 8 + h) * 1024 + gr) * 128 + d] = o;
                }
            }
        }
    }
}

// ---------------- launch ----------------

extern "C" void kernel_launch(void* const* d_in, const int* in_sizes, int n_in,
                              void* d_out, int out_size, void* d_ws, size_t ws_size,
                              hipStream_t stream) {
    (void)in_sizes; (void)n_in; (void)out_size;
    const float* v  = (const float*)d_in[0];   // (16,1024,1024) fp32
    const float* q  = (const float*)d_in[1];   // (16,128,1024)  fp32
    const float* Wv = (const float*)d_in[2];   // (3072,1024)    fp32
    const float* gv = (const float*)d_in[3];
    const float* bv = (const float*)d_in[4];   // (3072)
    const float* Wq = (const float*)d_in[5];   // (3072,1024)
    const float* gq = (const float*)d_in[6];
    const float* bq = (const float*)d_in[7];   // (3072)
    const float* hm = (const float*)d_in[8];   // (8,3072)
    const float* hb = (const float*)d_in[9];   // (8)
    float* out = (float*)d_out;                // fp32 output (16,8,1024,128) = 67 MB

    // workspace layout (floor 46.2 MB; +33.5 MB vb if available)
    char* ws = (char*)d_ws;
    float* ss   = (float*)ws;                          // 256 B
    float* cb   = (float*)(ws + 256);                  // 64 KB
    u16*   qbuf = (u16*)(ws + 256 + 65536);            // 2048*3072 bf16 = 12 MB
    u16*   tbuf = (u16*)(ws + 256 + 65536 + 12582912); // 16*8*128*1024 bf16 = 33.5 MB
    u16*   vb   = (u16*)(ws + 256 + 65536 + 12582912 + 33554432);  // optional 33.5 MB
    const size_t need_vb = 256 + 65536 + 12582912 + 33554432 + 33554432;  // ~80.2 MB
    const bool fullfat = (ws_size >= need_vb);

    // scratch in d_out (67.1 MB), all dead before the final gemm writes out:
    //   wvh 8*1024*3072 bf16 = 50.33 MB | qb 2048*1024 bf16 = 4.19 MB | wqb 3072*1024 bf16 = 6.29 MB
    u16* wvh = (u16*)d_out;
    u16* qb  = (u16*)((char*)d_out + 50331648);
    u16* wqb = (u16*)((char*)d_out + 54525952);   // ends at 60.8 MB < 67.1 MB

    zero_ss<<<1, 64, 0, stream>>>(ss);
    sumsq_k<<<dim3(256, 2), 256, 0, stream>>>(Wv, Wq, ss, 3072 * 1024);

    // wvh[h][c][k] = bf16(hm[h,k]*Wv[k,c])
    twvh_k<<<dim3(32, 96), dim3(32, 8), 0, stream>>>(Wv, hm, wvh);

    // bf16 copies of q and Wq so gemm<0> takes the pure-bf16 gload_lds path
    cvt_v<<<1024, 256, 0, stream>>>(q, qb, 2097152);
    cvt_v<<<1536, 256, 0, stream>>>(Wq, wqb, 3145728);

    // q_ = q * wn(Wq)^T + bq   (2048 x 3072)
    gemm_bt<0, true><<<dim3(24, 16, 1), 256, 0, stream>>>(
        qb, wqb, qbuf, ss, 1, gq, bq, nullptr, nullptr, 1024, 0, 0);

    // cb[b,hd] = sum_k bv*hm*q_
    const_k<<<64, 256, 0, stream>>>(qbuf, bv, hm, cb);

    // T[b,h,d,c] = sum_k q_[b,d,k] * wvh[h,c,k]  -- ONE GEMM: M=2048, N=8192, K=3072
    gemm8p<1><<<dim3(32, 8, 1), 512, 0, stream>>>(
        qbuf, wvh, tbuf, nullptr, nullptr, nullptr, nullptr, 3072, 0, 0);

    // logits[b,h,n,d] = scale_v * sum_c v[b,n,c]*T[b,hd,c] + cb[b,hd] + hbias[h]
    if (fullfat) {
        cvt_v<<<4096, 256, 0, stream>>>(v, vb, 16777216);
        gemm8p<2><<<dim3(4, 4, 16), 512, 0, stream>>>(
            vb, tbuf, out, ss, gv, cb, hb, 1024, 1048576, 1048576);
    } else {
        gemm_bt<2, false><<<dim3(8, 8, 16), 256, 0, stream>>>(
            v, tbuf, out, ss, 0, gv, nullptr, cb, hb, 1024, 1048576, 1048576);
    }
}

// Round 3
// 402.447 us; speedup vs baseline: 1.2352x; 1.0212x over previous
//
#include <hip/hip_runtime.h>
#include <hip/hip_bf16.h>
#include <math.h>

typedef unsigned short u16;
typedef unsigned int u32;

typedef __bf16 bf16x8 __attribute__((ext_vector_type(8)));
typedef float f32x4 __attribute__((ext_vector_type(4)));

union U8 { uint4 u; u16 s[8]; };

__device__ __forceinline__ float b2f(u16 x) {
    u32 y = ((u32)x) << 16;
    return __builtin_bit_cast(float, y);
}
__device__ __forceinline__ u16 f2b(float f) {
    u32 x = __builtin_bit_cast(u32, f);
    u32 r = x + 0x7fffu + ((x >> 16) & 1u);
    return (u16)(r >> 16);
}
// pack 8 fp32 -> 8 bf16 (one uint4)
__device__ __forceinline__ uint4 cvt8(float4 a, float4 b) {
    U8 o;
    o.s[0] = f2b(a.x); o.s[1] = f2b(a.y); o.s[2] = f2b(a.z); o.s[3] = f2b(a.w);
    o.s[4] = f2b(b.x); o.s[5] = f2b(b.y); o.s[6] = f2b(b.z); o.s[7] = f2b(b.w);
    return o.u;
}

// async global->LDS, 16 B per lane; LDS dest = wave-uniform base + lane*16
__device__ __forceinline__ void gload16(const u16* g, const u16* l) {
    __builtin_amdgcn_global_load_lds(
        (const __attribute__((address_space(1))) void*)g,
        (__attribute__((address_space(3))) void*)l, 16, 0, 0);
}

// ---------------- small kernels ----------------

__global__ void __launch_bounds__(64) zero_ss(float* ss) {
    if (threadIdx.x < 2) ss[threadIdx.x] = 0.f;
}

// sum of squares of Wv (y=0) / Wq (y=1), each 3072*1024 fp32
__global__ void __launch_bounds__(256) sumsq_k(const float* __restrict__ Wv,
                                               const float* __restrict__ Wq,
                                               float* __restrict__ ss, int n) {
    const float* W = (blockIdx.y == 0) ? Wv : Wq;
    float acc = 0.f;
    size_t stride = (size_t)gridDim.x * 256 * 8;
    for (size_t i = ((size_t)blockIdx.x * 256 + threadIdx.x) * 8; i < (size_t)n; i += stride) {
        float4 a = *(const float4*)(W + i);
        float4 b = *(const float4*)(W + i + 4);
        acc += a.x * a.x + a.y * a.y + a.z * a.z + a.w * a.w;
        acc += b.x * b.x + b.y * b.y + b.z * b.z + b.w * b.w;
    }
#pragma unroll
    for (int o = 32; o > 0; o >>= 1) acc += __shfl_down(acc, o, 64);
    __shared__ float red[4];
    int lane = threadIdx.x & 63, wv = threadIdx.x >> 6;
    if (lane == 0) red[wv] = acc;
    __syncthreads();
    if (threadIdx.x == 0) atomicAdd(&ss[blockIdx.y], red[0] + red[1] + red[2] + red[3]);
}

// wvh[h][c][k] = bf16(hm[h,k] * Wv[k,c])  -- fused transpose + 8-head scale
__global__ void __launch_bounds__(256) twvh_k(const float* __restrict__ Wv,
                                              const float* __restrict__ hm,
                                              u16* __restrict__ wvh) {
    __shared__ float t[32][33];
    int cx0 = blockIdx.x * 32;   // c base
    int ky0 = blockIdx.y * 32;   // k base
    int tx = threadIdx.x, ty = threadIdx.y;
#pragma unroll
    for (int j = ty; j < 32; j += 8)
        t[j][tx] = Wv[(size_t)(ky0 + j) * 1024 + cx0 + tx];
    __syncthreads();
    int k = ky0 + tx;
    float hv[8];
#pragma unroll
    for (int h = 0; h < 8; h++) hv[h] = hm[(size_t)h * 3072 + k];
#pragma unroll
    for (int j = ty; j < 32; j += 8) {
        float w = t[tx][j];           // Wv[k][cx0+j]
        int c = cx0 + j;
#pragma unroll
        for (int h = 0; h < 8; h++)
            wvh[(size_t)h * 3145728 + (size_t)c * 3072 + k] = f2b(hv[h] * w);
    }
}

// vb[i] = bf16(v[i]), n elements (generic fp32 -> bf16 cvt, grid-stride)
__global__ void __launch_bounds__(256) cvt_v(const float* __restrict__ v,
                                             u16* __restrict__ vb, int n) {
    size_t stride = (size_t)gridDim.x * 256 * 8;
    for (size_t i = ((size_t)blockIdx.x * 256 + threadIdx.x) * 8; i < (size_t)n; i += stride) {
        float4 a = *(const float4*)(v + i);
        float4 b = *(const float4*)(v + i + 4);
        *(uint4*)(vb + i) = cvt8(a, b);
    }
}

// cb[b*1024 + h*128 + d] = sum_k bv[k]*hm[h,k]*q_[b*128+d, k]   (fp32 acc)
__global__ void __launch_bounds__(256) const_k(const u16* __restrict__ qbuf,
                                               const float* __restrict__ bv,
                                               const float* __restrict__ hm,
                                               float* __restrict__ cb) {
    int idx = blockIdx.x * 256 + threadIdx.x;  // 0..16383
    int b = idx >> 10, hd = idx & 1023, h = hd >> 7, d = hd & 127;
    const u16* qr = qbuf + ((size_t)b * 128 + d) * 3072;
    const float* hr = hm + (size_t)h * 3072;
    float acc = 0.f;
    for (int k = 0; k < 3072; k += 8) {
        U8 uq; uq.u = *(const uint4*)(qr + k);
        float4 h0 = *(const float4*)(hr + k);
        float4 h1 = *(const float4*)(hr + k + 4);
        float4 b0 = *(const float4*)(bv + k);
        float4 b1 = *(const float4*)(bv + k + 4);
        acc += b2f(uq.s[0]) * h0.x * b0.x + b2f(uq.s[1]) * h0.y * b0.y +
               b2f(uq.s[2]) * h0.z * b0.z + b2f(uq.s[3]) * h0.w * b0.w +
               b2f(uq.s[4]) * h1.x * b1.x + b2f(uq.s[5]) * h1.y * b1.y +
               b2f(uq.s[6]) * h1.z * b1.z + b2f(uq.s[7]) * h1.w * b1.w;
    }
    cb[idx] = acc;
}

// ---------------- legacy 128x128 BT-GEMM (2-phase, __syncthreads) ----------------
// kept for EPI 0 (small N, more blocks) and the fp32-A fallback of EPI 2.
template <int EPI, bool A_BF16>
__global__ void __launch_bounds__(256)
gemm_bt(const void* __restrict__ Ap, const u16* __restrict__ Bp, void* __restrict__ C,
        const float* __restrict__ ss, int ss_idx, const float* __restrict__ g,
        const float* __restrict__ bias, const float* __restrict__ cb,
        const float* __restrict__ hbias, int kdim, size_t abatch, size_t bbatch) {
    constexpr int BK = 32;
    __shared__ __align__(16) u16 sA[2][128 * BK];
    __shared__ __align__(16) u16 sB[2][128 * BK];

    const int tid = threadIdx.x;
    const int lane = tid & 63, wv = tid >> 6;
    const int wm = (wv & 1) * 64, wn = (wv >> 1) * 64;
    const int lr = lane & 15, quad = lane >> 4;
    const int z = blockIdx.z;
    const int arow0 = blockIdx.y * 128;
    const int bcol0 = blockIdx.x * 128;

    const size_t aoff = (size_t)z * abatch;
    const size_t boff = (size_t)z * bbatch;

    const int srow = 16 * wv + (lane >> 2);
    const int qcg  = (lane & 3) ^ ((lane >> 3) & 3);
    const int lb0  = wv * 512;
    const int lb1  = lb0 + 2048;

    const u16* gB0 = Bp + boff + (size_t)(bcol0 + srow) * kdim + qcg * 8;
    const u16* gB1 = gB0 + (size_t)64 * kdim;

    const int r0 = tid >> 2, c0 = (tid & 3) * 8;
    const int w0 = r0 * 32 + (((tid & 3) ^ ((tid >> 3) & 3)) * 8);
    const int w1 = w0 + 2048;

    const u16* gA0 = nullptr; const u16* gA1 = nullptr;
    const float* fA0 = nullptr; const float* fA1 = nullptr;
    if constexpr (A_BF16) {
        gA0 = (const u16*)Ap + aoff + (size_t)(arow0 + srow) * kdim + qcg * 8;
        gA1 = gA0 + (size_t)64 * kdim;
    } else {
        fA0 = (const float*)Ap + aoff + (size_t)(arow0 + r0) * kdim + c0;
        fA1 = fA0 + (size_t)64 * kdim;
    }

    const int rsw = (quad ^ ((lr >> 1) & 3)) * 8;

    if constexpr (A_BF16) {
        gload16(gA0, sA[0] + lb0);
        gload16(gA1, sA[0] + lb1);
        gA0 += BK; gA1 += BK;
    } else {
        float4 x0 = *(const float4*)fA0, x1 = *(const float4*)(fA0 + 4);
        float4 y0 = *(const float4*)fA1, y1 = *(const float4*)(fA1 + 4);
        *(uint4*)(sA[0] + w0) = cvt8(x0, x1);
        *(uint4*)(sA[0] + w1) = cvt8(y0, y1);
        fA0 += BK; fA1 += BK;
    }
    gload16(gB0, sB[0] + lb0);
    gload16(gB1, sB[0] + lb1);
    gB0 += BK; gB1 += BK;

    f32x4 acc[4][4];
#pragma unroll
    for (int im = 0; im < 4; im++)
#pragma unroll
        for (int in = 0; in < 4; in++) acc[im][in] = (f32x4){0.f, 0.f, 0.f, 0.f};

    __syncthreads();

    int p = 0;
    for (int kt = 0; kt < kdim; kt += BK) {
        const bool more = (kt + BK < kdim);

        float4 ax0, ax1, ay0, ay1;
        if (more) {
            if constexpr (A_BF16) {
                gload16(gA0, sA[p ^ 1] + lb0);
                gload16(gA1, sA[p ^ 1] + lb1);
                gA0 += BK; gA1 += BK;
            } else {
                ax0 = *(const float4*)fA0; ax1 = *(const float4*)(fA0 + 4);
                ay0 = *(const float4*)fA1; ay1 = *(const float4*)(fA1 + 4);
                fA0 += BK; fA1 += BK;
            }
            gload16(gB0, sB[p ^ 1] + lb0);
            gload16(gB1, sB[p ^ 1] + lb1);
            gB0 += BK; gB1 += BK;
        }

        const u16* sAp = sA[p];
        const u16* sBp = sB[p];
        bf16x8 af[4], bfr[4];
#pragma unroll
        for (int im = 0; im < 4; im++)
            af[im] = *(const bf16x8*)(sAp + (wm + im * 16 + lr) * 32 + rsw);
#pragma unroll
        for (int in = 0; in < 4; in++)
            bfr[in] = *(const bf16x8*)(sBp + (wn + in * 16 + lr) * 32 + rsw);
#pragma unroll
        for (int im = 0; im < 4; im++)
#pragma unroll
            for (int in = 0; in < 4; in++)
                acc[im][in] = __builtin_amdgcn_mfma_f32_16x16x32_bf16(af[im], bfr[in], acc[im][in], 0, 0, 0);

        if (more) {
            if constexpr (!A_BF16) {
                u16* dA = sA[p ^ 1];
                *(uint4*)(dA + w0) = cvt8(ax0, ax1);
                *(uint4*)(dA + w1) = cvt8(ay0, ay1);
            }
        }
        __syncthreads();
        p ^= 1;
    }

    float scale = 1.f;
    if constexpr (EPI == 0 || EPI == 2) scale = g[0] / sqrtf(ss[ss_idx]);

#pragma unroll
    for (int im = 0; im < 4; im++) {
#pragma unroll
        for (int in = 0; in < 4; in++) {
#pragma unroll
            for (int reg = 0; reg < 4; reg++) {
                int gr = arow0 + wm + im * 16 + quad * 4 + reg;
                int gc = bcol0 + wn + in * 16 + lr;
                float val = acc[im][in][reg];
                if constexpr (EPI == 0) {
                    ((u16*)C)[(size_t)gr * 3072 + gc] = f2b(val * scale + bias[gc]);
                } else if constexpr (EPI == 1) {
                    size_t idx = (((size_t)(gr >> 7) * 8 + (gc >> 10)) * 128 + (gr & 127)) * 1024
                               + (gc & 1023);
                    ((u16*)C)[idx] = f2b(val);
                } else {
                    int h = gc >> 7, d = gc & 127;
                    float o = val * scale + cb[(size_t)z * 1024 + gc] + hbias[h];
                    ((float*)C)[(((size_t)z * 8 + h) * 1024 + gr) * 128 + d] = o;
                }
            }
        }
    }
}

// ---------------- 256x256 8-phase BT-GEMM (m201 structure: T1+T2+T3+T4+T5) ----------------
// C(M x N) = A(M x kdim) * Bt(N x kdim)^T. BM=BN=256, BK=64, 8 waves (2M x 4N),
// per-wave output 128x64 -> acc[8][4]. LDS 128 KiB: sA/sB[2 dbuf][256][64] bf16.
//
// LDS swizzle (T2, 3-bit): rows are 128 B -> bank index depends ONLY on the 16B
// group g (bank = g*4 mod 32). LDS[row][l] holds global group l ^ (row&7); the
// frag read for (ks,quad) uses slot (quad + 4ks) ^ (row&7): each ds_read_b128
// spreads its 64 lanes 8-per-16B-slot over all 32 banks = the 8-cycle floor.
// (Round-2's 1-bit XOR left all lanes in banks 0-15 -> 9.4M conflicts.)
// Applied by pre-swizzling gload_lds's per-lane GLOBAL source (LDS dest linear,
// rule #21) with the same involution; ks=1 address = ks0 address ^ 32 (u16).
//
// Phase structure per K-tile t (dbuf d = t&1), (ks,mh) quadrants, 16 MFMA each:
//   p0 (ks0,mh0): read B-ks0 frags(4)+A-mh0-ks0(4); stage A-calls{0,2} of t+1 -> dbuf d^1
//   p1 (ks0,mh1): read A-mh1-ks0(4);                stage B-calls{0,1}
//   p2 (ks1,mh0): read B-ks1(4)+A-mh0-ks1(4);       stage B-calls{2,3}
//   p3 (ks1,mh1): read A-mh1-ks1(4);                stage A-calls{1,3}
// Counted vmcnt gates (T4, never 0 mid-loop), placed after MFMA before bar2:
//   p0: vmcnt(2)  -- drains t-1.p3's A{1,3} (needed by this tile's p1/p3 reads)
//   p3: vmcnt(2)  -- drains t.p0-p2 (A{0,2}+B of t+1, needed by t+1.p0)
// Last tile (no staging): p0 uses vmcnt(0) once. Stages always target the
// opposite dbuf whose last reads finished >=1 barrier earlier -> race-free.
//
// T1 (EPI==1 only): 256 blocks, XCD = linear_id % 8; chunked so each XCD owns
// an 8(by) x 4(bx) rectangle -> per-XCD operand footprint 18 MB (round-2's
// one-by-row-per-XCD made each XCD sweep all 50 MB of B: FETCH 202 MB).
template <int EPI>
__global__ void __launch_bounds__(512, 2)
gemm8p(const u16* __restrict__ Ap, const u16* __restrict__ Bp, void* __restrict__ C,
       const float* __restrict__ ss, const float* __restrict__ g,
       const float* __restrict__ cb, const float* __restrict__ hbias,
       int kdim, size_t abatch, size_t bbatch) {
    __shared__ __align__(16) u16 sA[2][256 * 64];
    __shared__ __align__(16) u16 sB[2][256 * 64];

    const int tid = threadIdx.x;
    const int lane = tid & 63, wv = tid >> 6;
    const int wm = (wv & 1) * 128;            // M warp offset (2 warps)
    const int wn = (wv >> 1) * 64;            // N warp offset (4 warps)
    const int lr = lane & 15, quad = lane >> 4;
    const int z = blockIdx.z;

    int bx, by;
    if constexpr (EPI == 1) {
        // T1 chunked XCD swizzle: XCD k owns bx in [4k,4k+4), by 0..7
        int orig = blockIdx.y * 32 + blockIdx.x;       // gridDim = (32,8)
        int xcd = orig & 7, idx = orig >> 3;
        bx = (xcd << 2) | (idx & 3);
        by = idx >> 2;
    } else {
        bx = blockIdx.x; by = blockIdx.y;
    }
    const int arow0 = by * 256, bcol0 = bx * 256;

    const size_t aoff = (size_t)z * abatch, boff = (size_t)z * bbatch;

    // staging lane map: call = 64 rows x 64 cols (8KB); thread covers row tid>>3,
    // 16B-group tid&7, fetching pre-swizzled global group (tid&7) ^ (row&7)
    const int sg = (tid & 7) ^ ((tid >> 3) & 7);
    const u16* gA = Ap + aoff + (size_t)(arow0 + (tid >> 3)) * kdim + sg * 8;
    const u16* gB = Bp + boff + (size_t)(bcol0 + (tid >> 3)) * kdim + sg * 8;
    const size_t ldk64 = (size_t)64 * kdim;    // 64-row call stride (elements)
    const int ldst = wv * 512;                 // wave's u16 offset within a call

    // frag read bases (u16): row*64 + slot*8, slot = quad ^ (row&7); ks=1 -> ^32
    const int slot = (quad ^ (lane & 7)) * 8;
    const int rbA = (wm + lr) * 64 + slot;
    const int rbB = (wn + lr) * 64 + slot;

    f32x4 acc[8][4];
#pragma unroll
    for (int im = 0; im < 8; im++)
#pragma unroll
        for (int in = 0; in < 4; in++) acc[im][in] = (f32x4){0.f, 0.f, 0.f, 0.f};

    // ---- prologue: stage K-tile 0 into dbuf 0, full drain ----
    gload16(gA + 0 * ldk64, sA[0] + 0 * 4096 + ldst);
    gload16(gA + 1 * ldk64, sA[0] + 1 * 4096 + ldst);
    gload16(gA + 2 * ldk64, sA[0] + 2 * 4096 + ldst);
    gload16(gA + 3 * ldk64, sA[0] + 3 * 4096 + ldst);
    gload16(gB + 0 * ldk64, sB[0] + 0 * 4096 + ldst);
    gload16(gB + 1 * ldk64, sB[0] + 1 * 4096 + ldst);
    gload16(gB + 2 * ldk64, sB[0] + 2 * 4096 + ldst);
    gload16(gB + 3 * ldk64, sB[0] + 3 * 4096 + ldst);
    gA += 64; gB += 64;                        // -> K-tile 1 columns
    asm volatile("s_waitcnt vmcnt(0)" ::: "memory");
    __builtin_amdgcn_s_barrier();

    const int NT = kdim >> 6;
    bf16x8 af[4], bfr[4];
    for (int t = 0; t < NT; ++t) {
        const u16* sAd = sA[t & 1];
        const u16* sBd = sB[t & 1];
        u16* dA = sA[(t & 1) ^ 1];
        u16* dB = sB[(t & 1) ^ 1];
        const bool stg = (t + 1 < NT);

        // ---- phase 0: ks=0, mh=0 ----
#pragma unroll
        for (int n = 0; n < 4; n++) bfr[n] = *(const bf16x8*)(sBd + rbB + n * 1024);
#pragma unroll
        for (int j = 0; j < 4; j++) af[j] = *(const bf16x8*)(sAd + rbA + j * 1024);
        if (stg) {
            gload16(gA + 0 * ldk64, dA + 0 * 4096 + ldst);
            gload16(gA + 2 * ldk64, dA + 2 * 4096 + ldst);
        }
        __builtin_amdgcn_s_barrier();
        __builtin_amdgcn_s_setprio(1);
#pragma unroll
        for (int j = 0; j < 4; j++)
#pragma unroll
            for (int n = 0; n < 4; n++)
                acc[j][n] = __builtin_amdgcn_mfma_f32_16x16x32_bf16(af[j], bfr[n], acc[j][n], 0, 0, 0);
        __builtin_amdgcn_s_setprio(0);
        if (stg) asm volatile("s_waitcnt vmcnt(2)" ::: "memory");
        else     asm volatile("s_waitcnt vmcnt(0)" ::: "memory");
        __builtin_amdgcn_s_barrier();

        // ---- phase 1: ks=0, mh=1 ----
#pragma unroll
        for (int j = 0; j < 4; j++) af[j] = *(const bf16x8*)(sAd + rbA + (4 + j) * 1024);
        if (stg) {
            gload16(gB + 0 * ldk64, dB + 0 * 4096 + ldst);
            gload16(gB + 1 * ldk64, dB + 1 * 4096 + ldst);
        }
        __builtin_amdgcn_s_barrier();
        __builtin_amdgcn_s_setprio(1);
#pragma unroll
        for (int j = 0; j < 4; j++)
#pragma unroll
            for (int n = 0; n < 4; n++)
                acc[4 + j][n] = __builtin_amdgcn_mfma_f32_16x16x32_bf16(af[j], bfr[n], acc[4 + j][n], 0, 0, 0);
        __builtin_amdgcn_s_setprio(0);
        __builtin_amdgcn_s_barrier();

        // ---- phase 2: ks=1, mh=0 ----
#pragma unroll
        for (int n = 0; n < 4; n++) bfr[n] = *(const bf16x8*)(sBd + (rbB ^ 32) + n * 1024);
#pragma unroll
        for (int j = 0; j < 4; j++) af[j] = *(const bf16x8*)(sAd + (rbA ^ 32) + j * 1024);
        if (stg) {
            gload16(gB + 2 * ldk64, dB + 2 * 4096 + ldst);
            gload16(gB + 3 * ldk64, dB + 3 * 4096 + ldst);
        }
        __builtin_amdgcn_s_barrier();
        __builtin_amdgcn_s_setprio(1);
#pragma unroll
        for (int j = 0; j < 4; j++)
#pragma unroll
            for (int n = 0; n < 4; n++)
                acc[j][n] = __builtin_amdgcn_mfma_f32_16x16x32_bf16(af[j], bfr[n], acc[j][n], 0, 0, 0);
        __builtin_amdgcn_s_setprio(0);
        __builtin_amdgcn_s_barrier();

        // ---- phase 3: ks=1, mh=1 ----
#pragma unroll
        for (int j = 0; j < 4; j++) af[j] = *(const bf16x8*)(sAd + (rbA ^ 32) + (4 + j) * 1024);
        if (stg) {
            gload16(gA + 1 * ldk64, dA + 1 * 4096 + ldst);
            gload16(gA + 3 * ldk64, dA + 3 * 4096 + ldst);
        }
        __builtin_amdgcn_s_barrier();
        __builtin_amdgcn_s_setprio(1);
#pragma unroll
        for (int j = 0; j < 4; j++)
#pragma unroll
            for (int n = 0; n < 4; n++)
                acc[4 + j][n] = __builtin_amdgcn_mfma_f32_16x16x32_bf16(af[j], bfr[n], acc[4 + j][n], 0, 0, 0);
        __builtin_amdgcn_s_setprio(0);
        if (stg) asm volatile("s_waitcnt vmcnt(2)" ::: "memory");
        __builtin_amdgcn_s_barrier();

        gA += 64; gB += 64;
    }

    // ---- epilogue ----
    float scale = 1.f;
    if constexpr (EPI == 2) scale = g[0] / sqrtf(ss[0]);

#pragma unroll
    for (int im = 0; im < 8; im++) {
#pragma unroll
        for (int in = 0; in < 4; in++) {
#pragma unroll
            for (int reg = 0; reg < 4; reg++) {
                int gr = arow0 + wm + im * 16 + quad * 4 + reg;  // row (M)
                int gc = bcol0 + wn + in * 16 + lr;              // col (N)
                float val = acc[im][in][reg];
                if constexpr (EPI == 1) {
                    // gr = b*128+d (M=2048), gc = h*1024+c (N=8192) -> tbuf[b][h][d][c]
                    size_t idx = (((size_t)(gr >> 7) * 8 + (gc >> 10)) * 128 + (gr & 127)) * 1024
                               + (gc & 1023);
                    ((u16*)C)[idx] = f2b(val);
                } else {
                    int h = gc >> 7, d = gc & 127;
                    float o = val * scale + cb[(size_t)z * 1024 + gc] + hbias[h];
                    ((float*)C)[(((size_t)z * 8 + h) * 1024 + gr) * 128 + d] = o;
                }
            }
        }
    }
}

// ---------------- launch ----------------

extern "C" void kernel_launch(void* const* d_in, const int* in_sizes, int n_in,
                              void* d_out, int out_size, void* d_ws, size_t ws_size,
                              hipStream_t stream) {
    (void)in_sizes; (void)n_in; (void)out_size;
    const float* v  = (const float*)d_in[0];   // (16,1024,1024) fp32
    const float* q  = (const float*)d_in[1];   // (16,128,1024)  fp32
    const float* Wv = (const float*)d_in[2];   // (3072,1024)    fp32
    const float* gv = (const float*)d_in[3];
    const float* bv = (const float*)d_in[4];   // (3072)
    const float* Wq = (const float*)d_in[5];   // (3072,1024)
    const float* gq = (const float*)d_in[6];
    const float* bq = (const float*)d_in[7];   // (3072)
    const float* hm = (const float*)d_in[8];   // (8,3072)
    const float* hb = (const float*)d_in[9];   // (8)
    float* out = (float*)d_out;                // fp32 output (16,8,1024,128) = 67 MB

    // workspace layout (floor 46.2 MB; +33.5 MB vb if available)
    char* ws = (char*)d_ws;
    float* ss   = (float*)ws;                          // 256 B
    float* cb   = (float*)(ws + 256);                  // 64 KB
    u16*   qbuf = (u16*)(ws + 256 + 65536);            // 2048*3072 bf16 = 12 MB
    u16*   tbuf = (u16*)(ws + 256 + 65536 + 12582912); // 16*8*128*1024 bf16 = 33.5 MB
    u16*   vb   = (u16*)(ws + 256 + 65536 + 12582912 + 33554432);  // optional 33.5 MB
    const size_t need_vb = 256 + 65536 + 12582912 + 33554432 + 33554432;  // ~80.2 MB
    const bool fullfat = (ws_size >= need_vb);

    // scratch in d_out (67.1 MB), all dead before the final gemm writes out:
    //   wvh 8*1024*3072 bf16 = 50.33 MB | qb 2048*1024 bf16 = 4.19 MB | wqb 3072*1024 bf16 = 6.29 MB
    u16* wvh = (u16*)d_out;
    u16* qb  = (u16*)((char*)d_out + 50331648);
    u16* wqb = (u16*)((char*)d_out + 54525952);   // ends at 60.8 MB < 67.1 MB

    zero_ss<<<1, 64, 0, stream>>>(ss);
    sumsq_k<<<dim3(256, 2), 256, 0, stream>>>(Wv, Wq, ss, 3072 * 1024);

    // wvh[h][c][k] = bf16(hm[h,k]*Wv[k,c])
    twvh_k<<<dim3(32, 96), dim3(32, 8), 0, stream>>>(Wv, hm, wvh);

    // bf16 copies of q and Wq so gemm<0> takes the pure-bf16 gload_lds path
    cvt_v<<<1024, 256, 0, stream>>>(q, qb, 2097152);
    cvt_v<<<1536, 256, 0, stream>>>(Wq, wqb, 3145728);

    // q_ = q * wn(Wq)^T + bq   (2048 x 3072)
    gemm_bt<0, true><<<dim3(24, 16, 1), 256, 0, stream>>>(
        qb, wqb, qbuf, ss, 1, gq, bq, nullptr, nullptr, 1024, 0, 0);

    // cb[b,hd] = sum_k bv*hm*q_
    const_k<<<64, 256, 0, stream>>>(qbuf, bv, hm, cb);

    // T[b,h,d,c] = sum_k q_[b,d,k] * wvh[h,c,k]  -- ONE GEMM: M=2048, N=8192, K=3072
    gemm8p<1><<<dim3(32, 8, 1), 512, 0, stream>>>(
        qbuf, wvh, tbuf, nullptr, nullptr, nullptr, nullptr, 3072, 0, 0);

    // logits[b,h,n,d] = scale_v * sum_c v[b,n,c]*T[b,hd,c] + cb[b,hd] + hbias[h]
    if (fullfat) {
        cvt_v<<<4096, 256, 0, stream>>>(v, vb, 16777216);
        gemm8p<2><<<dim3(4, 4, 16), 512, 0, stream>>>(
            vb, tbuf, out, ss, gv, cb, hb, 1024, 1048576, 1048576);
    } else {
        gemm_bt<2, false><<<dim3(8, 8, 16), 256, 0, stream>>>(
            v, tbuf, out, ss, 0, gv, nullptr, cb, hb, 1024, 1048576, 1048576);
    }
}